// Round 5
// baseline (328.805 us; speedup 1.0000x reference)
//
#include <hip/hip_runtime.h>

typedef __attribute__((ext_vector_type(8))) __bf16 bf16x8;
typedef __attribute__((ext_vector_type(4))) float f32x4;
typedef __attribute__((ext_vector_type(16))) float f32x16;
typedef __attribute__((ext_vector_type(4))) unsigned int u32x4;
typedef __attribute__((ext_vector_type(8))) _Float16 f16x8;
typedef __attribute__((ext_vector_type(4))) _Float16 f16x4;
typedef unsigned short us;

#define SEQ 2048
#define DIM 1024
#define NH 16
#define HDIM 64

// 0.125 * log2(e): folded into Q projection so softmax uses native exp2
#define QSCALE 0.1803368801111204f

__device__ inline us f2bf(float f) {
    unsigned u = __builtin_bit_cast(unsigned, f);
    u += 0x7FFFu + ((u >> 16) & 1u);   // RNE
    return (us)(u >> 16);
}

__device__ inline unsigned sx32(unsigned v) {   // partner-lane (lane^32) value
    return (unsigned)__shfl_xor((int)v, 32);
}

// async global->LDS, 16B per lane; LDS dest = wave-uniform base + lane*16
__device__ __forceinline__ void gload16(const us* g, us* l) {
    __builtin_amdgcn_global_load_lds(
        (const __attribute__((address_space(1))) unsigned int*)(const void*)g,
        (__attribute__((address_space(3))) unsigned int*)(void*)l, 16, 0, 0);
}

// ---------- cast fp32 -> bf16 ----------
__global__ __launch_bounds__(256) void cast_many(
    const float* __restrict__ s0, const float* __restrict__ s1,
    const float* __restrict__ s2, const float* __restrict__ s3,
    us* __restrict__ dst, int n_each)
{
    const float* src = (blockIdx.y == 0) ? s0 : (blockIdx.y == 1) ? s1
                     : (blockIdx.y == 2) ? s2 : s3;
    size_t base = (size_t)blockIdx.y * (size_t)n_each;
    int i = (blockIdx.x * 256 + threadIdx.x) * 4;
    if (i < n_each) {
        float4 v = *(const float4*)(src + i);
        ushort4 o;
        o.x = f2bf(v.x); o.y = f2bf(v.y); o.z = f2bf(v.z); o.w = f2bf(v.w);
        *(ushort4*)(dst + base + i) = o;
    }
}

// ---------- mask bitpack: mask[2][2048] bytes -> 128 uint32 words ----------
__global__ __launch_bounds__(64) void maskpack(
    const unsigned char* __restrict__ mask, unsigned* __restrict__ mw)
{
    int t = blockIdx.x * 64 + threadIdx.x;   // 0..127
    unsigned wv = 0;
#pragma unroll
    for (int j = 0; j < 32; j++) wv |= (mask[t * 32 + j] ? 1u : 0u) << j;
    mw[t] = wv;
}

// ---------- bf16 GEMM core: C[M,N] = (A[M,K] @ W[N,K]^T + bias) * oscale ----------
#define BM 128
#define BN 128
#define BK 64

__device__ __forceinline__ void gemm_core(
    const us* __restrict__ A, const us* __restrict__ W,
    const float* __restrict__ bias, void* __restrict__ out,
    int M, int N, int K, int mode, float oscale)
{
    __shared__ us lA[BM * BK];
    __shared__ us lB[BN * BK];

    const int tid  = threadIdx.x;
    const int lane = tid & 63;
    const int w    = tid >> 6;
    const int wm   = w >> 1, wn = w & 1;
    const int m0   = blockIdx.y * BM, n0 = blockIdx.x * BN;
    const int g    = lane >> 4, li = lane & 15;

    const f32x4 fz = {0.f, 0.f, 0.f, 0.f};
    f32x4 acc[4][4];
#pragma unroll
    for (int i = 0; i < 4; i++)
#pragma unroll
        for (int j = 0; j < 4; j++) acc[i][j] = fz;

    for (int k0 = 0; k0 < K; k0 += BK) {
#pragma unroll
        for (int i = 0; i < 4; i++) {
            int v = tid + i * 256;           // 16B unit index, 1024 total
            int row = v >> 3, c8 = (v & 7) * 8;
            gload16(&A[(size_t)(m0 + row) * K + k0 + c8], &lA[v * 8]);
            gload16(&W[(size_t)(n0 + row) * K + k0 + c8], &lB[v * 8]);
        }
        __syncthreads();                     // drains vmcnt(0) incl. load_lds
#pragma unroll
        for (int kk = 0; kk < 2; kk++) {
            bf16x8 af[4], bfr[4];
#pragma unroll
            for (int i = 0; i < 4; i++)
                af[i] = *(const bf16x8*)&lA[(wm * 64 + i * 16 + li) * BK + kk * 32 + g * 8];
#pragma unroll
            for (int j = 0; j < 4; j++)
                bfr[j] = *(const bf16x8*)&lB[(wn * 64 + j * 16 + li) * BK + kk * 32 + g * 8];
#pragma unroll
            for (int i = 0; i < 4; i++)
#pragma unroll
                for (int j = 0; j < 4; j++)
                    acc[i][j] = __builtin_amdgcn_mfma_f32_16x16x32_bf16(
                        af[i], bfr[j], acc[i][j], 0, 0, 0);
        }
        __syncthreads();
    }

    const int r0 = g * 4;
#pragma unroll
    for (int i = 0; i < 4; i++) {
#pragma unroll
        for (int j = 0; j < 4; j++) {
            int col = n0 + wn * 64 + j * 16 + li;
            float bs = bias[col];
#pragma unroll
            for (int r = 0; r < 4; r++) {
                int row = m0 + wm * 64 + i * 16 + r0 + r;
                float val = (acc[i][j][r] + bs) * oscale;
                if (mode == 2) {
                    ((float*)out)[(size_t)row * N + col] = val;
                } else {
                    int b = row >> 11, s = row & (SEQ - 1);
                    int h = col >> 6, hd = col & (HDIM - 1);
                    size_t idx = (mode == 0)
                        ? ((((size_t)b * NH + h) * SEQ + s) * HDIM + hd)
                        : ((((size_t)b * NH + h) * HDIM + hd) * SEQ + s);
                    ((us*)out)[idx] = f2bf(val);
                }
            }
        }
    }
}

__global__ __launch_bounds__(256) void gemm_qkv(
    const us* __restrict__ xq, const us* __restrict__ xk, const us* __restrict__ xv,
    const us* __restrict__ wq, const us* __restrict__ wk, const us* __restrict__ wv,
    const float* __restrict__ bq, const float* __restrict__ bk, const float* __restrict__ bv,
    us* __restrict__ Qb, us* __restrict__ Kb, us* __restrict__ VTb)
{
    int z = blockIdx.z;
    if (z == 0)      gemm_core(xq, wq, bq, Qb,  2 * SEQ, DIM, DIM, 0, QSCALE);
    else if (z == 1) gemm_core(xk, wk, bk, Kb,  2 * SEQ, DIM, DIM, 0, 1.0f);
    else             gemm_core(xv, wv, bv, VTb, 2 * SEQ, DIM, DIM, 1, 1.0f);
}

__global__ __launch_bounds__(256) void gemm_one(
    const us* __restrict__ A, const us* __restrict__ W,
    const float* __restrict__ bias, float* __restrict__ out)
{
    gemm_core(A, W, bias, out, 2 * SEQ, DIM, DIM, 2, 1.0f);
}

// ---------- attention, split-KV: wave = (32-q tile, half of KV) ----------
// S^T = mfma(K,Q): lane owns q=lane&31; 16 scores at key=(r&3)+8*(r>>2)+4*hi.
// Deferred-max (skip rescale+cross-half reduce unless max grows >8) and
// per-lane partial l (combined once post-loop). Partial O stored /l in f16.
__global__ __launch_bounds__(256, 4) void attn_split(
    const us* __restrict__ Qb, const us* __restrict__ Kb,
    const us* __restrict__ VT, const unsigned* __restrict__ mw,
    _Float16* __restrict__ opart, float* __restrict__ mlpart)
{
    const int tid  = threadIdx.x;
    const int w    = tid >> 6, lane = tid & 63;
    const int unit = blockIdx.x * 4 + w;          // 0..4095
    const int tile = unit >> 1, half = unit & 1;  // 2048 tiles x 2 halves
    const int bh   = tile >> 6, qt = tile & 63;
    const int b    = bh >> 4;
    const int q0   = qt * 32;
    const int ql   = lane & 31, hi = lane >> 5;
    const int kv0  = half * 1024, kv1 = kv0 + 1024;

    const us* Qp  = Qb + (((size_t)bh * SEQ) + q0 + ql) * HDIM + hi * 8;
    const us* Kp  = Kb + ((size_t)bh * SEQ + ql) * HDIM + hi * 8;
    const us* Vp0 = VT + ((size_t)bh * HDIM + ql) * SEQ + hi * 8;
    const us* Vp1 = Vp0 + 32 * SEQ;

    bf16x8 qf[4];
#pragma unroll
    for (int t = 0; t < 4; t++) qf[t] = *(const bf16x8*)(Qp + t * 16);

    const f32x16 z16 = {0,0,0,0,0,0,0,0,0,0,0,0,0,0,0,0};
    f32x16 o0 = z16, o1 = z16;
    float mrun = -1e30f, lrun = 0.f;   // lrun = per-lane partial (own 16 keys/step)

    bf16x8 kf[4];
#pragma unroll
    for (int t = 0; t < 4; t++) kf[t] = *(const bf16x8*)(Kp + (size_t)kv0 * HDIM + t * 16);

    for (int kv = kv0; kv < kv1; kv += 32) {
        f32x16 s = z16;
#pragma unroll
        for (int t = 0; t < 4; t++)
            s = __builtin_amdgcn_mfma_f32_32x32x16_bf16(kf[t], qf[t], s, 0, 0, 0);

        if (kv + 32 < kv1) {                      // prefetch next K tile
            const us* Kn = Kp + (size_t)(kv + 32) * HDIM;
#pragma unroll
            for (int t = 0; t < 4; t++) kf[t] = *(const bf16x8*)(Kn + t * 16);
        }
        bf16x8 vf0[2], vf1[2];                    // V for THIS step (softmax covers latency)
#pragma unroll
        for (int t = 0; t < 2; t++) {
            vf0[t] = *(const bf16x8*)(Vp0 + kv + t * 16);
            vf1[t] = *(const bf16x8*)(Vp1 + kv + t * 16);
        }

        unsigned m32 = (unsigned)__builtin_amdgcn_readfirstlane(
            (int)mw[b * 64 + (kv >> 5)]);

        // per-lane max over own 16 scores (tree)
        float t8[8];
#pragma unroll
        for (int j = 0; j < 8; j++) t8[j] = fmaxf(s[j], s[j + 8]);
#pragma unroll
        for (int j = 0; j < 4; j++) t8[j] = fmaxf(t8[j], t8[j + 4]);
        float pmax = fmaxf(fmaxf(t8[0], t8[1]), fmaxf(t8[2], t8[3]));

        if (!__all(pmax <= mrun + 8.f)) {         // rare: real rescale
            float pm = fmaxf(pmax, __shfl_xor(pmax, 32));
            float nm = fmaxf(mrun, pm);
            float corr = __builtin_amdgcn_exp2f(mrun - nm);
            lrun *= corr;
#pragma unroll
            for (int j = 0; j < 16; j++) { o0[j] *= corr; o1[j] *= corr; }
            mrun = nm;
        }

        float p[16];
#pragma unroll
        for (int r = 0; r < 16; r++) p[r] = __builtin_amdgcn_exp2f(s[r] - mrun);
        if (m32) {   // key-padding mask: zero masked columns post-exp
            unsigned ms = hi ? (m32 >> 4) : m32;
#pragma unroll
            for (int r = 0; r < 16; r++)
                if ((ms >> ((r & 3) + 8 * (r >> 2))) & 1) p[r] = 0.f;
        }
        float a8[8];
#pragma unroll
        for (int j = 0; j < 8; j++) a8[j] = p[j] + p[j + 8];
#pragma unroll
        for (int j = 0; j < 4; j++) a8[j] += a8[j + 4];
        lrun += (a8[0] + a8[1]) + (a8[2] + a8[3]);

        // pack P -> bf16 B-fragments (4-shuffle exchange: each shfl serves both dirs)
        unsigned pw[8];
#pragma unroll
        for (int j = 0; j < 8; j++)
            asm("v_cvt_pk_bf16_f32 %0, %1, %2"
                : "=v"(pw[j]) : "v"(p[2 * j]), "v"(p[2 * j + 1]));

        unsigned y0 = sx32(hi ? pw[0] : pw[2]);
        unsigned y1 = sx32(hi ? pw[1] : pw[3]);
        unsigned y2 = sx32(hi ? pw[4] : pw[6]);
        unsigned y3 = sx32(hi ? pw[5] : pw[7]);

        u32x4 t0, t1;
        t0.x = hi ? y0    : pw[0];
        t0.y = hi ? y1    : pw[1];
        t0.z = hi ? pw[2] : y0;
        t0.w = hi ? pw[3] : y1;
        t1.x = hi ? y2    : pw[4];
        t1.y = hi ? y3    : pw[5];
        t1.z = hi ? pw[6] : y2;
        t1.w = hi ? pw[7] : y3;
        bf16x8 pa0 = __builtin_bit_cast(bf16x8, t0);
        bf16x8 pa1 = __builtin_bit_cast(bf16x8, t1);

        o0 = __builtin_amdgcn_mfma_f32_32x32x16_bf16(vf0[0], pa0, o0, 0, 0, 0);
        o0 = __builtin_amdgcn_mfma_f32_32x32x16_bf16(vf0[1], pa1, o0, 0, 0, 0);
        o1 = __builtin_amdgcn_mfma_f32_32x32x16_bf16(vf1[0], pa0, o1, 0, 0, 0);
        o1 = __builtin_amdgcn_mfma_f32_32x32x16_bf16(vf1[1], pa1, o1, 0, 0, 0);
    }

    float lh  = lrun + __shfl_xor(lrun, 32);      // combine lane-pair partials once
    float inv = __builtin_amdgcn_rcpf(lh);

    size_t orow = (size_t)half * 65536 + (size_t)bh * SEQ + q0 + ql;
    _Float16* od = opart + orow * 64;
#pragma unroll
    for (int g2 = 0; g2 < 4; g2++) {
        f16x4 v0, v1;
#pragma unroll
        for (int j = 0; j < 4; j++) {
            v0[j] = (_Float16)(o0[4 * g2 + j] * inv);
            v1[j] = (_Float16)(o1[4 * g2 + j] * inv);
        }
        *(f16x4*)(od + 8 * g2 + 4 * hi)      = v0;   // d = 8*g2 + 4*hi + j
        *(f16x4*)(od + 32 + 8 * g2 + 4 * hi) = v1;   // d = 32 + ...
    }
    if (hi == 0) {
        float2 mlv; mlv.x = mrun; mlv.y = lh;
        *(float2*)&mlpart[orow * 2] = mlv;
    }
}

// ---------- combine the two KV halves -> AO (bf16 [B,S,H,HD]) ----------
__global__ __launch_bounds__(256) void attn_combine(
    const _Float16* __restrict__ op, const float* __restrict__ ml,
    us* __restrict__ AO)
{
    int t   = blockIdx.x * 256 + threadIdx.x;   // 65536 rows * 8 chunks
    int row = t >> 3, dc = (t & 7) * 8;
    int bh  = row >> 11, q = row & (SEQ - 1);
    int b   = bh >> 4, h = bh & 15;

    float2 ml0 = *(const float2*)&ml[(size_t)row * 2];
    float2 ml1 = *(const float2*)&ml[(size_t)(65536 + row) * 2];
    float M  = fmaxf(ml0.x, ml1.x);
    float w0 = ml0.y * __builtin_amdgcn_exp2f(ml0.x - M);
    float w1 = ml1.y * __builtin_amdgcn_exp2f(ml1.x - M);
    float wi = __builtin_amdgcn_rcpf(w0 + w1);
    float a0 = w0 * wi, a1 = w1 * wi;

    f16x8 v0 = *(const f16x8*)(op + (size_t)row * 64 + dc);
    f16x8 v1 = *(const f16x8*)(op + 4194304 + (size_t)row * 64 + dc);

    ushort4 r0, r1;
    r0.x = f2bf(a0 * (float)v0[0] + a1 * (float)v1[0]);
    r0.y = f2bf(a0 * (float)v0[1] + a1 * (float)v1[1]);
    r0.z = f2bf(a0 * (float)v0[2] + a1 * (float)v1[2]);
    r0.w = f2bf(a0 * (float)v0[3] + a1 * (float)v1[3]);
    r1.x = f2bf(a0 * (float)v0[4] + a1 * (float)v1[4]);
    r1.y = f2bf(a0 * (float)v0[5] + a1 * (float)v1[5]);
    r1.z = f2bf(a0 * (float)v0[6] + a1 * (float)v1[6]);
    r1.w = f2bf(a0 * (float)v0[7] + a1 * (float)v1[7]);

    us* dst = AO + ((size_t)b * SEQ + q) * DIM + h * HDIM + dc;
    *(ushort4*)dst       = r0;
    *(ushort4*)(dst + 4) = r1;
}

// ---------- launch ----------
extern "C" void kernel_launch(void* const* d_in, const int* in_sizes, int n_in,
                              void* d_out, int out_size, void* d_ws, size_t ws_size,
                              hipStream_t stream)
{
    const float* q  = (const float*)d_in[0];
    const float* k  = (const float*)d_in[1];
    const float* v  = (const float*)d_in[2];
    const unsigned char* mask = (const unsigned char*)d_in[3];
    const float* Wq = (const float*)d_in[4];
    const float* bq = (const float*)d_in[5];
    const float* Wk = (const float*)d_in[6];
    const float* bk = (const float*)d_in[7];
    const float* Wv = (const float*)d_in[8];
    const float* bv = (const float*)d_in[9];
    const float* Wo = (const float*)d_in[10];
    const float* bo = (const float*)d_in[11];

    us* ws  = (us*)d_ws;
    us* xq  = ws;                    // [4096,1024] bf16 each (dead after gemm_qkv)
    us* xk  = ws + 4194304;
    us* xv  = ws + 8388608;
    us* wqb = ws + 12582912;         // [1024,1024] bf16 each (wq/wk/wv dead after qkv)
    us* wkb = ws + 13631488;
    us* wvb = ws + 14680064;
    us* wob = ws + 15728640;         // live until final gemm
    us* Qb  = ws + 16777216;         // [B,H,S,HD] bf16 (pre-scaled by QSCALE)
    us* Kb  = ws + 20971520;         // [B,H,S,HD]
    us* VTb = ws + 25165824;         // [B,H,HD,S]
    us* AO  = ws + 29360128;         // [B*S, D] bf16
    unsigned* mwords = (unsigned*)(ws + 33554432);   // 128 words
    // partials overlay the dead xq/xk/xv region:
    _Float16* opart  = (_Float16*)ws;                 // [2][32][2048][64] f16 = 16.8MB
    float*    mlpart = (float*)(ws + 8388608 + 524288); // [2][65536][2] f32 = 1MB (in xv)

    cast_many<<<dim3(4096, 3), 256, 0, stream>>>(q, k, v, q, xq, 4194304);
    cast_many<<<dim3(1024, 4), 256, 0, stream>>>(Wq, Wk, Wv, Wo, wqb, 1048576);
    maskpack<<<dim3(2), 64, 0, stream>>>(mask, mwords);

    gemm_qkv<<<dim3(DIM / BN, (2 * SEQ) / BM, 3), 256, 0, stream>>>(
        xq, xk, xv, wqb, wkb, wvb, bq, bk, bv, Qb, Kb, VTb);

    attn_split<<<dim3(1024), 256, 0, stream>>>(Qb, Kb, VTb, mwords, opart, mlpart);
    attn_combine<<<dim3(2048), 256, 0, stream>>>(opart, mlpart, AO);

    gemm_one<<<dim3(DIM / BN, (2 * SEQ) / BM), 256, 0, stream>>>(AO, wob, bo, (float*)d_out);
}

// Round 6
// 263.747 us; speedup vs baseline: 1.2467x; 1.2467x over previous
//
#include <hip/hip_runtime.h>

typedef __attribute__((ext_vector_type(8))) __bf16 bf16x8;
typedef __attribute__((ext_vector_type(4))) float f32x4;
typedef __attribute__((ext_vector_type(16))) float f32x16;
typedef __attribute__((ext_vector_type(4))) unsigned int u32x4;
typedef __attribute__((ext_vector_type(8))) _Float16 f16x8;
typedef __attribute__((ext_vector_type(4))) _Float16 f16x4;
typedef unsigned short us;

#define SEQ 2048
#define DIM 1024
#define NH 16
#define HDIM 64

// 0.125 * log2(e): folded into Q projection so softmax uses native exp2
#define QSCALE 0.1803368801111204f

__device__ inline us f2bf(float f) {
    unsigned u = __builtin_bit_cast(unsigned, f);
    u += 0x7FFFu + ((u >> 16) & 1u);   // RNE
    return (us)(u >> 16);
}

__device__ inline unsigned sx32(unsigned v) {   // partner-lane (lane^32) value
    return (unsigned)__shfl_xor((int)v, 32);
}

// fragment-major layouts (one 2048-elem block per (bh, s/32)):
//   QK: element (s,d):  block*2048 + (d>>4)*512 + ((s&31) + 32*((d>>3)&1))*8 + (d&7)
//   V : element (d,s):  block*2048 + ((d>>5)*2 + ((s>>4)&1))*512 + ((d&31) + 32*((s>>3)&1))*8 + (s&7)
__device__ __forceinline__ size_t qk_idx(int bh, int s, int d) {
    return (((size_t)bh * 64 + (s >> 5)) << 11) + ((d >> 4) << 9)
         + (((s & 31) + (((d >> 3) & 1) << 5)) << 3) + (d & 7);
}
__device__ __forceinline__ size_t v_idx(int bh, int d, int s) {
    return (((size_t)bh * 64 + (s >> 5)) << 11) + ((((d >> 5) << 1) + ((s >> 4) & 1)) << 9)
         + (((d & 31) + (((s >> 3) & 1) << 5)) << 3) + (s & 7);
}

// async global->LDS, 16B per lane; LDS dest = wave-uniform base + lane*16
__device__ __forceinline__ void gload16(const us* g, us* l) {
    __builtin_amdgcn_global_load_lds(
        (const __attribute__((address_space(1))) unsigned int*)(const void*)g,
        (__attribute__((address_space(3))) unsigned int*)(void*)l, 16, 0, 0);
}

// ---------- cast fp32 -> bf16 ----------
__global__ __launch_bounds__(256) void cast_many(
    const float* __restrict__ s0, const float* __restrict__ s1,
    const float* __restrict__ s2, const float* __restrict__ s3,
    us* __restrict__ dst, int n_each)
{
    const float* src = (blockIdx.y == 0) ? s0 : (blockIdx.y == 1) ? s1
                     : (blockIdx.y == 2) ? s2 : s3;
    size_t base = (size_t)blockIdx.y * (size_t)n_each;
    int i = (blockIdx.x * 256 + threadIdx.x) * 4;
    if (i < n_each) {
        float4 v = *(const float4*)(src + i);
        ushort4 o;
        o.x = f2bf(v.x); o.y = f2bf(v.y); o.z = f2bf(v.z); o.w = f2bf(v.w);
        *(ushort4*)(dst + base + i) = o;
    }
}

// ---------- mask bitpack: mask[2][2048] bytes -> 128 uint32 words ----------
__global__ __launch_bounds__(64) void maskpack(
    const unsigned char* __restrict__ mask, unsigned* __restrict__ mw)
{
    int t = blockIdx.x * 64 + threadIdx.x;   // 0..127
    unsigned wv = 0;
#pragma unroll
    for (int j = 0; j < 32; j++) wv |= (mask[t * 32 + j] ? 1u : 0u) << j;
    mw[t] = wv;
}

// ---------- bf16 GEMM core: C[M,N] = (A[M,K] @ W[N,K]^T + bias) * oscale ----------
// mode 0: out bf16, fragment-major QK layout
// mode 1: out bf16, fragment-major V layout
// mode 2: out fp32, row-major [M,N]              (final projection)
#define BM 128
#define BN 128
#define BK 64

__device__ __forceinline__ void gemm_core(
    const us* __restrict__ A, const us* __restrict__ W,
    const float* __restrict__ bias, void* __restrict__ out,
    int M, int N, int K, int mode, float oscale)
{
    __shared__ us lA[BM * BK];
    __shared__ us lB[BN * BK];

    const int tid  = threadIdx.x;
    const int lane = tid & 63;
    const int w    = tid >> 6;
    const int wm   = w >> 1, wn = w & 1;
    const int m0   = blockIdx.y * BM, n0 = blockIdx.x * BN;
    const int g    = lane >> 4, li = lane & 15;

    const f32x4 fz = {0.f, 0.f, 0.f, 0.f};
    f32x4 acc[4][4];
#pragma unroll
    for (int i = 0; i < 4; i++)
#pragma unroll
        for (int j = 0; j < 4; j++) acc[i][j] = fz;

    for (int k0 = 0; k0 < K; k0 += BK) {
#pragma unroll
        for (int i = 0; i < 4; i++) {
            int v = tid + i * 256;           // 16B unit index, 1024 total
            int row = v >> 3, c8 = (v & 7) * 8;
            gload16(&A[(size_t)(m0 + row) * K + k0 + c8], &lA[v * 8]);
            gload16(&W[(size_t)(n0 + row) * K + k0 + c8], &lB[v * 8]);
        }
        __syncthreads();                     // drains vmcnt(0) incl. load_lds
#pragma unroll
        for (int kk = 0; kk < 2; kk++) {
            bf16x8 af[4], bfr[4];
#pragma unroll
            for (int i = 0; i < 4; i++)
                af[i] = *(const bf16x8*)&lA[(wm * 64 + i * 16 + li) * BK + kk * 32 + g * 8];
#pragma unroll
            for (int j = 0; j < 4; j++)
                bfr[j] = *(const bf16x8*)&lB[(wn * 64 + j * 16 + li) * BK + kk * 32 + g * 8];
#pragma unroll
            for (int i = 0; i < 4; i++)
#pragma unroll
                for (int j = 0; j < 4; j++)
                    acc[i][j] = __builtin_amdgcn_mfma_f32_16x16x32_bf16(
                        af[i], bfr[j], acc[i][j], 0, 0, 0);
        }
        __syncthreads();
    }

    const int r0 = g * 4;
#pragma unroll
    for (int i = 0; i < 4; i++) {
#pragma unroll
        for (int j = 0; j < 4; j++) {
            int col = n0 + wn * 64 + j * 16 + li;
            float bs = bias[col];
#pragma unroll
            for (int r = 0; r < 4; r++) {
                int row = m0 + wm * 64 + i * 16 + r0 + r;
                float val = (acc[i][j][r] + bs) * oscale;
                if (mode == 2) {
                    ((float*)out)[(size_t)row * N + col] = val;
                } else {
                    int s = row & (SEQ - 1);
                    int bh = ((row >> 11) << 4) + (col >> 6);
                    int d  = col & (HDIM - 1);
                    size_t idx = (mode == 0) ? qk_idx(bh, s, d) : v_idx(bh, d, s);
                    ((us*)out)[idx] = f2bf(val);
                }
            }
        }
    }
}

__global__ __launch_bounds__(256) void gemm_qkv(
    const us* __restrict__ xq, const us* __restrict__ xk, const us* __restrict__ xv,
    const us* __restrict__ wq, const us* __restrict__ wk, const us* __restrict__ wv,
    const float* __restrict__ bq, const float* __restrict__ bk, const float* __restrict__ bv,
    us* __restrict__ Qb, us* __restrict__ Kb, us* __restrict__ VTb)
{
    int z = blockIdx.z;
    if (z == 0)      gemm_core(xq, wq, bq, Qb,  2 * SEQ, DIM, DIM, 0, QSCALE);
    else if (z == 1) gemm_core(xk, wk, bk, Kb,  2 * SEQ, DIM, DIM, 0, 1.0f);
    else             gemm_core(xv, wv, bv, VTb, 2 * SEQ, DIM, DIM, 1, 1.0f);
}

__global__ __launch_bounds__(256) void gemm_one(
    const us* __restrict__ A, const us* __restrict__ W,
    const float* __restrict__ bias, float* __restrict__ out)
{
    gemm_core(A, W, bias, out, 2 * SEQ, DIM, DIM, 2, 1.0f);
}

// ---------- attention, split-KV: wave = (32-q tile, half of KV) ----------
// All Q/K/V global loads are fragment-major: wave-uniform base + lane*16B.
__global__ __launch_bounds__(256, 4) void attn_split(
    const us* __restrict__ Qb, const us* __restrict__ Kb,
    const us* __restrict__ VT, const unsigned* __restrict__ mw,
    _Float16* __restrict__ opart, float* __restrict__ mlpart)
{
    const int tid  = threadIdx.x;
    const int w    = tid >> 6, lane = tid & 63;
    const int unit = blockIdx.x * 4 + w;          // 0..4095
    const int tile = unit >> 1, half = unit & 1;  // 2048 tiles x 2 halves
    const int bh   = tile >> 6, qt = tile & 63;
    const int b    = bh >> 4;
    const int q0   = qt * 32;
    const int ql   = lane & 31, hi = lane >> 5;
    const int kv0  = half * 1024, kv1 = kv0 + 1024;

    const us* Qf = Qb + (((size_t)bh * 64 + qt) << 11) + lane * 8;
    const us* Kf = Kb + (((size_t)bh * 64) << 11) + lane * 8;
    const us* Vf = VT + (((size_t)bh * 64) << 11) + lane * 8;

    bf16x8 qf[4];
#pragma unroll
    for (int t = 0; t < 4; t++) qf[t] = *(const bf16x8*)(Qf + t * 512);

    const f32x16 z16 = {0,0,0,0,0,0,0,0,0,0,0,0,0,0,0,0};
    f32x16 o0 = z16, o1 = z16;
    float mrun = -1e30f, lrun = 0.f;   // lrun = per-lane partial (own 16 keys/step)

    bf16x8 kf[4];
#pragma unroll
    for (int t = 0; t < 4; t++)
        kf[t] = *(const bf16x8*)(Kf + ((size_t)(kv0 >> 5) << 11) + t * 512);

    for (int kv = kv0; kv < kv1; kv += 32) {
        const size_t koff = (size_t)(kv >> 5) << 11;

        f32x16 s = z16;
#pragma unroll
        for (int t = 0; t < 4; t++)
            s = __builtin_amdgcn_mfma_f32_32x32x16_bf16(kf[t], qf[t], s, 0, 0, 0);

        if (kv + 32 < kv1) {                      // prefetch next K tile
            const us* Kn = Kf + koff + 2048;
#pragma unroll
            for (int t = 0; t < 4; t++) kf[t] = *(const bf16x8*)(Kn + t * 512);
        }
        bf16x8 vf0[2], vf1[2];                    // V for THIS step (softmax covers latency)
#pragma unroll
        for (int t = 0; t < 2; t++) {
            vf0[t] = *(const bf16x8*)(Vf + koff + t * 512);
            vf1[t] = *(const bf16x8*)(Vf + koff + 1024 + t * 512);
        }

        unsigned m32 = (unsigned)__builtin_amdgcn_readfirstlane(
            (int)mw[b * 64 + (kv >> 5)]);

        // per-lane max over own 16 scores (tree)
        float t8[8];
#pragma unroll
        for (int j = 0; j < 8; j++) t8[j] = fmaxf(s[j], s[j + 8]);
#pragma unroll
        for (int j = 0; j < 4; j++) t8[j] = fmaxf(t8[j], t8[j + 4]);
        float pmax = fmaxf(fmaxf(t8[0], t8[1]), fmaxf(t8[2], t8[3]));

        if (!__all(pmax <= mrun + 8.f)) {         // rare: real rescale
            float pm = fmaxf(pmax, __shfl_xor(pmax, 32));
            float nm = fmaxf(mrun, pm);
            float corr = __builtin_amdgcn_exp2f(mrun - nm);
            lrun *= corr;
#pragma unroll
            for (int j = 0; j < 16; j++) { o0[j] *= corr; o1[j] *= corr; }
            mrun = nm;
        }

        float p[16];
#pragma unroll
        for (int r = 0; r < 16; r++) p[r] = __builtin_amdgcn_exp2f(s[r] - mrun);
        if (m32) {   // key-padding mask: zero masked columns post-exp
            unsigned ms = hi ? (m32 >> 4) : m32;
#pragma unroll
            for (int r = 0; r < 16; r++)
                if ((ms >> ((r & 3) + 8 * (r >> 2))) & 1) p[r] = 0.f;
        }
        float a8[8];
#pragma unroll
        for (int j = 0; j < 8; j++) a8[j] = p[j] + p[j + 8];
#pragma unroll
        for (int j = 0; j < 4; j++) a8[j] += a8[j + 4];
        lrun += (a8[0] + a8[1]) + (a8[2] + a8[3]);

        // pack P -> bf16 B-fragments (4-shuffle exchange: each shfl serves both dirs)
        unsigned pw[8];
#pragma unroll
        for (int j = 0; j < 8; j++)
            asm("v_cvt_pk_bf16_f32 %0, %1, %2"
                : "=v"(pw[j]) : "v"(p[2 * j]), "v"(p[2 * j + 1]));

        unsigned y0 = sx32(hi ? pw[0] : pw[2]);
        unsigned y1 = sx32(hi ? pw[1] : pw[3]);
        unsigned y2 = sx32(hi ? pw[4] : pw[6]);
        unsigned y3 = sx32(hi ? pw[5] : pw[7]);

        u32x4 t0, t1;
        t0.x = hi ? y0    : pw[0];
        t0.y = hi ? y1    : pw[1];
        t0.z = hi ? pw[2] : y0;
        t0.w = hi ? pw[3] : y1;
        t1.x = hi ? y2    : pw[4];
        t1.y = hi ? y3    : pw[5];
        t1.z = hi ? pw[6] : y2;
        t1.w = hi ? pw[7] : y3;
        bf16x8 pa0 = __builtin_bit_cast(bf16x8, t0);
        bf16x8 pa1 = __builtin_bit_cast(bf16x8, t1);

        o0 = __builtin_amdgcn_mfma_f32_32x32x16_bf16(vf0[0], pa0, o0, 0, 0, 0);
        o0 = __builtin_amdgcn_mfma_f32_32x32x16_bf16(vf0[1], pa1, o0, 0, 0, 0);
        o1 = __builtin_amdgcn_mfma_f32_32x32x16_bf16(vf1[0], pa0, o1, 0, 0, 0);
        o1 = __builtin_amdgcn_mfma_f32_32x32x16_bf16(vf1[1], pa1, o1, 0, 0, 0);
    }

    float lh  = lrun + __shfl_xor(lrun, 32);      // combine lane-pair partials once
    float inv = __builtin_amdgcn_rcpf(lh);

    size_t orow = (size_t)half * 65536 + (size_t)bh * SEQ + q0 + ql;
    _Float16* od = opart + orow * 64;
#pragma unroll
    for (int g2 = 0; g2 < 4; g2++) {
        f16x4 v0, v1;
#pragma unroll
        for (int j = 0; j < 4; j++) {
            v0[j] = (_Float16)(o0[4 * g2 + j] * inv);
            v1[j] = (_Float16)(o1[4 * g2 + j] * inv);
        }
        *(f16x4*)(od + 8 * g2 + 4 * hi)      = v0;   // d = 8*g2 + 4*hi + j
        *(f16x4*)(od + 32 + 8 * g2 + 4 * hi) = v1;   // d = 32 + ...
    }
    if (hi == 0) {
        float2 mlv; mlv.x = mrun; mlv.y = lh;
        *(float2*)&mlpart[orow * 2] = mlv;
    }
}

// ---------- combine the two KV halves -> AO (bf16 [B,S,H,HD]) ----------
__global__ __launch_bounds__(256) void attn_combine(
    const _Float16* __restrict__ op, const float* __restrict__ ml,
    us* __restrict__ AO)
{
    int t   = blockIdx.x * 256 + threadIdx.x;   // 65536 rows * 8 chunks
    int row = t >> 3, dc = (t & 7) * 8;
    int bh  = row >> 11, q = row & (SEQ - 1);
    int b   = bh >> 4, h = bh & 15;

    float2 ml0 = *(const float2*)&ml[(size_t)row * 2];
    float2 ml1 = *(const float2*)&ml[(size_t)(65536 + row) * 2];
    float M  = fmaxf(ml0.x, ml1.x);
    float w0 = ml0.y * __builtin_amdgcn_exp2f(ml0.x - M);
    float w1 = ml1.y * __builtin_amdgcn_exp2f(ml1.x - M);
    float wi = __builtin_amdgcn_rcpf(w0 + w1);
    float a0 = w0 * wi, a1 = w1 * wi;

    f16x8 v0 = *(const f16x8*)(op + (size_t)row * 64 + dc);
    f16x8 v1 = *(const f16x8*)(op + 4194304 + (size_t)row * 64 + dc);

    ushort4 r0, r1;
    r0.x = f2bf(a0 * (float)v0[0] + a1 * (float)v1[0]);
    r0.y = f2bf(a0 * (float)v0[1] + a1 * (float)v1[1]);
    r0.z = f2bf(a0 * (float)v0[2] + a1 * (float)v1[2]);
    r0.w = f2bf(a0 * (float)v0[3] + a1 * (float)v1[3]);
    r1.x = f2bf(a0 * (float)v0[4] + a1 * (float)v1[4]);
    r1.y = f2bf(a0 * (float)v0[5] + a1 * (float)v1[5]);
    r1.z = f2bf(a0 * (float)v0[6] + a1 * (float)v1[6]);
    r1.w = f2bf(a0 * (float)v0[7] + a1 * (float)v1[7]);

    us* dst = AO + ((size_t)b * SEQ + q) * DIM + h * HDIM + dc;
    *(ushort4*)dst       = r0;
    *(ushort4*)(dst + 4) = r1;
}

// ---------- launch ----------
extern "C" void kernel_launch(void* const* d_in, const int* in_sizes, int n_in,
                              void* d_out, int out_size, void* d_ws, size_t ws_size,
                              hipStream_t stream)
{
    const float* q  = (const float*)d_in[0];
    const float* k  = (const float*)d_in[1];
    const float* v  = (const float*)d_in[2];
    const unsigned char* mask = (const unsigned char*)d_in[3];
    const float* Wq = (const float*)d_in[4];
    const float* bq = (const float*)d_in[5];
    const float* Wk = (const float*)d_in[6];
    const float* bk = (const float*)d_in[7];
    const float* Wv = (const float*)d_in[8];
    const float* bv = (const float*)d_in[9];
    const float* Wo = (const float*)d_in[10];
    const float* bo = (const float*)d_in[11];

    us* ws  = (us*)d_ws;
    us* xq  = ws;                    // [4096,1024] bf16 each (dead after gemm_qkv)
    us* xk  = ws + 4194304;
    us* xv  = ws + 8388608;
    us* wqb = ws + 12582912;         // [1024,1024] bf16 each
    us* wkb = ws + 13631488;
    us* wvb = ws + 14680064;
    us* wob = ws + 15728640;         // live until final gemm
    us* Qb  = ws + 16777216;         // fragment-major QK layout (pre-scaled by QSCALE)
    us* Kb  = ws + 20971520;
    us* VTb = ws + 25165824;         // fragment-major V layout
    us* AO  = ws + 29360128;         // [B*S, D] bf16
    unsigned* mwords = (unsigned*)(ws + 33554432);   // 128 words
    // partials overlay the dead xq/xk/xv region:
    _Float16* opart  = (_Float16*)ws;                 // [2][32][2048][64] f16 = 16.8MB
    float*    mlpart = (float*)(ws + 8388608 + 524288); // [2][65536][2] f32 = 1MB (in xv)

    cast_many<<<dim3(4096, 3), 256, 0, stream>>>(q, k, v, q, xq, 4194304);
    cast_many<<<dim3(1024, 4), 256, 0, stream>>>(Wq, Wk, Wv, Wo, wqb, 1048576);
    maskpack<<<dim3(2), 64, 0, stream>>>(mask, mwords);

    gemm_qkv<<<dim3(DIM / BN, (2 * SEQ) / BM, 3), 256, 0, stream>>>(
        xq, xk, xv, wqb, wkb, wvb, bq, bk, bv, Qb, Kb, VTb);

    attn_split<<<dim3(1024), 256, 0, stream>>>(Qb, Kb, VTb, mwords, opart, mlpart);
    attn_combine<<<dim3(2048), 256, 0, stream>>>(opart, mlpart, AO);

    gemm_one<<<dim3(DIM / BN, (2 * SEQ) / BM), 256, 0, stream>>>(AO, wob, bo, (float*)d_out);
}